// Round 1
// baseline (232.535 us; speedup 1.0000x reference)
//
#include <hip/hip_runtime.h>
#include <hip/hip_bf16.h>
#include <stdint.h>

#define M_DIM 2048
#define N_DIM 4096
#define K_DIM 4096
#define NGROUP 32
#define GSIZE 128

// GEMM tiling
#define BM 128
#define BN 128
#define BK 64
#define LPAD 8              // +8 bf16 = +16B pad -> row stride 144B = 36 dwords
#define LDR (BK + LPAD)     // 72 elements per LDS row

typedef __attribute__((ext_vector_type(8))) short bf16x8_t;   // 8 bf16 in 4 VGPRs
typedef __attribute__((ext_vector_type(4))) float f32x4_t;

static __device__ __forceinline__ unsigned short f2bf(float f) {
    union { float f; unsigned u; } v; v.f = f;
    unsigned r = v.u + 0x7fff + ((v.u >> 16) & 1);   // RNE; inputs are exact ints anyway
    return (unsigned short)(r >> 16);
}

// ---------------------------------------------------------------------------
// Phase 1: per-token asymmetric quantization.
// One block per token row. Produces centered_x = (q - zp) as bf16 (exact:
// |centered| <= 255 < 256) and x_scale per token.
// ---------------------------------------------------------------------------
__global__ __launch_bounds__(256) void quant_x_kernel(
        const float* __restrict__ x,
        unsigned short* __restrict__ A,      // [M][K] bf16 bits
        float* __restrict__ xscale)          // [M]
{
    const int s = blockIdx.x;
    const int t = threadIdx.x;
    const float* xrow = x + (size_t)s * K_DIM;

    float xv[16];
    float vmin = 1e38f, vmax = -1e38f;
#pragma unroll
    for (int p = 0; p < 4; ++p) {
        float4 v = *((const float4*)(xrow + p * 1024) + t);
        xv[p*4+0] = v.x; xv[p*4+1] = v.y; xv[p*4+2] = v.z; xv[p*4+3] = v.w;
        vmin = fminf(vmin, fminf(fminf(v.x, v.y), fminf(v.z, v.w)));
        vmax = fmaxf(vmax, fmaxf(fmaxf(v.x, v.y), fmaxf(v.z, v.w)));
    }
    // wave (64-lane) butterfly reduce
#pragma unroll
    for (int off = 32; off > 0; off >>= 1) {
        vmin = fminf(vmin, __shfl_xor(vmin, off));
        vmax = fmaxf(vmax, __shfl_xor(vmax, off));
    }
    __shared__ float smin[4], smax[4];
    const int wave = t >> 6;
    if ((t & 63) == 0) { smin[wave] = vmin; smax[wave] = vmax; }
    __syncthreads();
    vmin = fminf(fminf(smin[0], smin[1]), fminf(smin[2], smin[3]));
    vmax = fmaxf(fmaxf(smax[0], smax[1]), fmaxf(smax[2], smax[3]));

    float sc = (vmax - vmin) / 255.0f;          // match ref: (max-min)/(QMAX-QMIN)
    sc = fmaxf(sc, 1e-5f);                      // clip(.., 1e-5, None)
    float zp = rintf(-vmin / sc);
    zp = fminf(fmaxf(zp, 0.0f), 255.0f);

#pragma unroll
    for (int p = 0; p < 4; ++p) {
        ushort4 o;
        float q0 = fminf(fmaxf(rintf(xv[p*4+0] / sc) + zp, 0.0f), 255.0f);
        float q1 = fminf(fmaxf(rintf(xv[p*4+1] / sc) + zp, 0.0f), 255.0f);
        float q2 = fminf(fmaxf(rintf(xv[p*4+2] / sc) + zp, 0.0f), 255.0f);
        float q3 = fminf(fmaxf(rintf(xv[p*4+3] / sc) + zp, 0.0f), 255.0f);
        o.x = f2bf(q0 - zp); o.y = f2bf(q1 - zp);
        o.z = f2bf(q2 - zp); o.w = f2bf(q3 - zp);
        *(ushort4*)(A + (size_t)s * K_DIM + p * 1024 + t * 4) = o;
    }
    if (t == 0) xscale[s] = sc;
}

// ---------------------------------------------------------------------------
// Phase 2: weight dequant. centered_w = code - wzp[o][g], exact small int in
// bf16. Layout stays [N][K] (row-major per output = "B^T" for the GEMM).
// ---------------------------------------------------------------------------
__global__ __launch_bounds__(256) void dequant_w_kernel(
        const int* __restrict__ qw,          // [N][K] codes 0..15 as int32
        const int* __restrict__ wzp,         // [N][32]
        unsigned short* __restrict__ Bt)     // [N][K] bf16 bits
{
    const size_t idx = (size_t)blockIdx.x * 256 + threadIdx.x;  // 8 codes each
    const size_t base = idx * 8;                                // flat [N][K]
    const int n = (int)(base >> 12);          // /4096
    const int k = (int)(base & (K_DIM - 1));
    const int g = k >> 7;                     // /128 (8 codes never cross a group)
    const float zp = (float)wzp[n * NGROUP + g];

    int4 c0 = *(const int4*)(qw + base);
    int4 c1 = *(const int4*)(qw + base + 4);
    ushort4 o0, o1;
    o0.x = f2bf((float)c0.x - zp); o0.y = f2bf((float)c0.y - zp);
    o0.z = f2bf((float)c0.z - zp); o0.w = f2bf((float)c0.w - zp);
    o1.x = f2bf((float)c1.x - zp); o1.y = f2bf((float)c1.y - zp);
    o1.z = f2bf((float)c1.z - zp); o1.w = f2bf((float)c1.w - zp);
    *(ushort4*)(Bt + base)     = o0;
    *(ushort4*)(Bt + base + 4) = o1;
}

// ---------------------------------------------------------------------------
// Phase 3: grouped-scale GEMM. C[m][n] = xscale[m] *
//   sum_g wscales[n][g] * sum_{k in g} Ax[m][k]*Wc[n][k]   + bias[n]
// 128x128 tile / block, 4 waves, each wave a 64x64 quadrant as 4x4 of
// 16x16x32 bf16 MFMA. Per-group fp32 fold every 2 BK=64 stages.
// ---------------------------------------------------------------------------
__global__ __launch_bounds__(256) void gemm_kernel(
        const unsigned short* __restrict__ A,    // [M][K] bf16
        const unsigned short* __restrict__ Bt,   // [N][K] bf16
        const float* __restrict__ xscale,        // [M]
        const float* __restrict__ wscales,       // [N][32]
        const float* __restrict__ bias,          // [N]
        float* __restrict__ out)                 // [M][N] f32
{
    __shared__ unsigned short As[BM * LDR];
    __shared__ unsigned short Bs[BN * LDR];

    const int tid  = threadIdx.x;
    const int bm   = blockIdx.y;
    const int bn   = blockIdx.x;
    const int wave = tid >> 6;
    const int lane = tid & 63;
    const int wr   = (wave >> 1) * 64;   // wave row offset within 128-tile
    const int wc   = (wave & 1) * 64;    // wave col offset
    const int lrow  = lane & 15;
    const int lquad = lane >> 4;         // 0..3

    f32x4_t cacc[4][4];
    f32x4_t gacc[4][4];
    const f32x4_t zero4 = {0.f, 0.f, 0.f, 0.f};
#pragma unroll
    for (int i = 0; i < 4; ++i)
#pragma unroll
        for (int j = 0; j < 4; ++j) { cacc[i][j] = zero4; gacc[i][j] = zero4; }

    const unsigned short* Ab = A  + (size_t)(bm * BM) * K_DIM;
    const unsigned short* Bb = Bt + (size_t)(bn * BN) * K_DIM;

    const int srow   = tid >> 3;   // 0..31: row within staging pass
    const int schunk = tid & 7;    // 8B-elem (16B) chunk within BK=64 row

    for (int kt = 0; kt < K_DIM / BK; ++kt) {   // 64 stages
        const int k0 = kt * BK;
        __syncthreads();
#pragma unroll
        for (int p = 0; p < 4; ++p) {
            const int r = p * 32 + srow;
            uint4 av = *(const uint4*)(Ab + (size_t)r * K_DIM + k0 + schunk * 8);
            *(uint4*)(As + r * LDR + schunk * 8) = av;
            uint4 bv = *(const uint4*)(Bb + (size_t)r * K_DIM + k0 + schunk * 8);
            *(uint4*)(Bs + r * LDR + schunk * 8) = bv;
        }
        __syncthreads();

#pragma unroll
        for (int ks = 0; ks < 2; ++ks) {
            bf16x8_t af[4], bf[4];
#pragma unroll
            for (int i = 0; i < 4; ++i)
                af[i] = *(const bf16x8_t*)(As + (wr + i * 16 + lrow) * LDR + ks * 32 + lquad * 8);
#pragma unroll
            for (int j = 0; j < 4; ++j)
                bf[j] = *(const bf16x8_t*)(Bs + (wc + j * 16 + lrow) * LDR + ks * 32 + lquad * 8);
#pragma unroll
            for (int i = 0; i < 4; ++i)
#pragma unroll
                for (int j = 0; j < 4; ++j)
                    gacc[i][j] = __builtin_amdgcn_mfma_f32_16x16x32_bf16(
                        af[i], bf[j], gacc[i][j], 0, 0, 0);
        }

        if (kt & 1) {                          // end of a 128-wide K group
            const int g = kt >> 1;
#pragma unroll
            for (int j = 0; j < 4; ++j) {
                const int n = bn * BN + wc + j * 16 + lrow;
                const float scl = wscales[n * NGROUP + g];
#pragma unroll
                for (int i = 0; i < 4; ++i) {
                    cacc[i][j] += gacc[i][j] * scl;
                    gacc[i][j] = zero4;
                }
            }
        }
    }

    // Epilogue: C/D layout col=lane&15, row=lquad*4+reg  [m89/m91 verified]
    const int m0 = bm * BM + wr;
    const int n0 = bn * BN + wc;
#pragma unroll
    for (int i = 0; i < 4; ++i) {
#pragma unroll
        for (int r = 0; r < 4; ++r) {
            const int m = m0 + i * 16 + lquad * 4 + r;
            const float xs = xscale[m];
#pragma unroll
            for (int j = 0; j < 4; ++j) {
                const int n = n0 + j * 16 + lrow;
                out[(size_t)m * N_DIM + n] = cacc[i][j][r] * xs + bias[n];
            }
        }
    }
}

extern "C" void kernel_launch(void* const* d_in, const int* in_sizes, int n_in,
                              void* d_out, int out_size, void* d_ws, size_t ws_size,
                              hipStream_t stream) {
    const float* x     = (const float*)d_in[0];
    const int*   qw    = (const int*)d_in[1];
    const float* wsc   = (const float*)d_in[2];
    const int*   wzp   = (const int*)d_in[3];
    const float* bias  = (const float*)d_in[4];
    float* out = (float*)d_out;

    // workspace layout
    unsigned short* A = (unsigned short*)d_ws;                           // 16 MiB
    float* xscale = (float*)((char*)d_ws + (size_t)M_DIM * K_DIM * 2);   // 8 KiB
    unsigned short* Bt = (unsigned short*)((char*)xscale + M_DIM * 4);   // 32 MiB

    quant_x_kernel<<<M_DIM, 256, 0, stream>>>(x, A, xscale);
    dequant_w_kernel<<<(size_t)N_DIM * K_DIM / 8 / 256, 256, 0, stream>>>(qw, wzp, Bt);
    dim3 grid(N_DIM / BN, M_DIM / BM);
    gemm_kernel<<<grid, 256, 0, stream>>>(A, Bt, xscale, wsc, bias, out);
}

// Round 2
// 222.068 us; speedup vs baseline: 1.0471x; 1.0471x over previous
//
#include <hip/hip_runtime.h>
#include <hip/hip_bf16.h>
#include <stdint.h>

#define M_DIM 2048
#define N_DIM 4096
#define K_DIM 4096
#define NGROUP 32
#define GSIZE 128

// GEMM tiling
#define BM 128
#define BN 128
#define BK 64          // 64 bf16 = 128 B = 8 chunks of 16 B per LDS row (no pad)

typedef __attribute__((ext_vector_type(8))) short bf16x8_t;   // 8 bf16 in 4 VGPRs
typedef __attribute__((ext_vector_type(4))) float f32x4_t;

static __device__ __forceinline__ unsigned short f2bf(float f) {
    union { float f; unsigned u; } v; v.f = f;
    unsigned r = v.u + 0x7fff + ((v.u >> 16) & 1);   // RNE; inputs are exact ints anyway
    return (unsigned short)(r >> 16);
}

// global -> LDS direct DMA, 16 B per lane. LDS dst is wave-uniform base +
// lane*16 (m104/m108), so `l` must be wave-uniform; data placement is chosen
// via the per-lane global address. CK-style address-space casts via uintptr_t.
static __device__ __forceinline__ void gl2lds16(const void* g, void* l) {
    auto gp = (const __attribute__((address_space(1))) unsigned int*)(uintptr_t)g;
    auto lp = (__attribute__((address_space(3))) unsigned int*)(uintptr_t)l;
    __builtin_amdgcn_global_load_lds(gp, lp, 16, 0, 0);
}

// ---------------------------------------------------------------------------
// Fused prep: blocks [0,2048) per-token activation quant; blocks [2048, ...)
// weight dequant. Both HBM-bound and independent -> one launch, full overlap.
// ---------------------------------------------------------------------------
#define QUANT_BLOCKS M_DIM
#define DEQ_BLOCKS ((N_DIM * K_DIM) / 4 / 256)   // 4 codes per thread

__global__ __launch_bounds__(256) void prep_kernel(
        const float* __restrict__ x,
        const int* __restrict__ qw,          // [N][K] codes 0..15 as int32
        const int* __restrict__ wzp,         // [N][32]
        unsigned short* __restrict__ A,      // [M][K] bf16 bits (centered_x)
        unsigned short* __restrict__ Bt,     // [N][K] bf16 bits (centered_w)
        float* __restrict__ xscale)          // [M]
{
    const int t = threadIdx.x;
    if (blockIdx.x < QUANT_BLOCKS) {
        // ---- per-token asymmetric quantization, one block per token ----
        const int s = blockIdx.x;
        const float* xrow = x + (size_t)s * K_DIM;

        float xv[16];
        float vmin = 1e38f, vmax = -1e38f;
#pragma unroll
        for (int p = 0; p < 4; ++p) {
            float4 v = *((const float4*)(xrow + p * 1024) + t);
            xv[p*4+0] = v.x; xv[p*4+1] = v.y; xv[p*4+2] = v.z; xv[p*4+3] = v.w;
            vmin = fminf(vmin, fminf(fminf(v.x, v.y), fminf(v.z, v.w)));
            vmax = fmaxf(vmax, fmaxf(fmaxf(v.x, v.y), fmaxf(v.z, v.w)));
        }
#pragma unroll
        for (int off = 32; off > 0; off >>= 1) {
            vmin = fminf(vmin, __shfl_xor(vmin, off));
            vmax = fmaxf(vmax, __shfl_xor(vmax, off));
        }
        __shared__ float smin[4], smax[4];
        const int wave = t >> 6;
        if ((t & 63) == 0) { smin[wave] = vmin; smax[wave] = vmax; }
        __syncthreads();
        vmin = fminf(fminf(smin[0], smin[1]), fminf(smin[2], smin[3]));
        vmax = fmaxf(fmaxf(smax[0], smax[1]), fmaxf(smax[2], smax[3]));

        float sc = (vmax - vmin) / 255.0f;
        sc = fmaxf(sc, 1e-5f);
        float zp = rintf(-vmin / sc);
        zp = fminf(fmaxf(zp, 0.0f), 255.0f);

#pragma unroll
        for (int p = 0; p < 4; ++p) {
            ushort4 o;
            float q0 = fminf(fmaxf(rintf(xv[p*4+0] / sc) + zp, 0.0f), 255.0f);
            float q1 = fminf(fmaxf(rintf(xv[p*4+1] / sc) + zp, 0.0f), 255.0f);
            float q2 = fminf(fmaxf(rintf(xv[p*4+2] / sc) + zp, 0.0f), 255.0f);
            float q3 = fminf(fmaxf(rintf(xv[p*4+3] / sc) + zp, 0.0f), 255.0f);
            o.x = f2bf(q0 - zp); o.y = f2bf(q1 - zp);
            o.z = f2bf(q2 - zp); o.w = f2bf(q3 - zp);
            *(ushort4*)(A + (size_t)s * K_DIM + p * 1024 + t * 4) = o;
        }
        if (t == 0) xscale[s] = sc;
    } else {
        // ---- weight dequant: 4 codes/thread, contiguous 16B load, 8B store
        const size_t base = ((size_t)(blockIdx.x - QUANT_BLOCKS) * 256 + t) * 4;
        const int n = (int)(base >> 12);          // /4096
        const int g = (int)((base >> 7) & 31);    // group (4 codes never cross)
        const float zp = (float)wzp[n * NGROUP + g];

        int4 c = *(const int4*)(qw + base);
        ushort4 o;
        o.x = f2bf((float)c.x - zp); o.y = f2bf((float)c.y - zp);
        o.z = f2bf((float)c.z - zp); o.w = f2bf((float)c.w - zp);
        *(ushort4*)(Bt + base) = o;
    }
}

// ---------------------------------------------------------------------------
// Grouped-scale GEMM. C[m][n] = xscale[m] *
//   sum_g wscales[n][g] * sum_{k in g} Ax[m][k]*Wc[n][k]   + bias[n]
// 128x128 tile / block, 4 waves, each wave a 64x64 quadrant as 4x4 of
// 16x16x32 bf16 MFMA. Staging via global_load_lds (16B DMA, no LDS writes).
// LDS layout: row-major [128][64] bf16, 16B chunk c of row r stored at
// position c ^ (r&7) -> fragment reads hit all 8 bank groups (conflict-free).
// ---------------------------------------------------------------------------
__global__ __launch_bounds__(256) void gemm_kernel(
        const unsigned short* __restrict__ A,    // [M][K] bf16
        const unsigned short* __restrict__ Bt,   // [N][K] bf16
        const float* __restrict__ xscale,        // [M]
        const float* __restrict__ wscales,       // [N][32]
        const float* __restrict__ bias,          // [N]
        float* __restrict__ out)                 // [M][N] f32
{
    __shared__ __align__(16) unsigned short As[BM * BK];   // 16 KiB
    __shared__ __align__(16) unsigned short Bs[BN * BK];   // 16 KiB

    const int tid  = threadIdx.x;
    const int bm   = blockIdx.y;
    const int bn   = blockIdx.x;
    const int wave = tid >> 6;
    const int lane = tid & 63;
    const int wr   = (wave >> 1) * 64;   // wave row offset within 128-tile
    const int wc   = (wave & 1) * 64;    // wave col offset
    const int lrow  = lane & 15;
    const int lquad = lane >> 4;         // 0..3
    const int l7    = lrow & 7;          // row&7 for swizzle decode

    // staging mapping: per global_load_lds instr a wave covers 8 rows x 8 chunks
    const int srow8 = lane >> 3;         // row within 8-row slab (== row&7)
    const int cdat  = (lane & 7) ^ srow8; // source chunk for this LDS slot

    f32x4_t cacc[4][4];
    f32x4_t gacc[4][4];
    const f32x4_t zero4 = {0.f, 0.f, 0.f, 0.f};
#pragma unroll
    for (int i = 0; i < 4; ++i)
#pragma unroll
        for (int j = 0; j < 4; ++j) { cacc[i][j] = zero4; gacc[i][j] = zero4; }

    const unsigned short* Ab = A  + (size_t)(bm * BM) * K_DIM;
    const unsigned short* Bb = Bt + (size_t)(bn * BN) * K_DIM;

    for (int kt = 0; kt < K_DIM / BK; ++kt) {   // 64 stages
        const int k0 = kt * BK;
        __syncthreads();
#pragma unroll
        for (int p = 0; p < 4; ++p) {
            const int rbase = p * 32 + wave * 8;        // wave-uniform
            const int r = rbase + srow8;
            gl2lds16(Ab + (size_t)r * K_DIM + k0 + cdat * 8, As + rbase * BK);
            gl2lds16(Bb + (size_t)r * K_DIM + k0 + cdat * 8, Bs + rbase * BK);
        }
        __syncthreads();

#pragma unroll
        for (int ks = 0; ks < 2; ++ks) {
            bf16x8_t af[4], bf[4];
            const int kc = ks * 4 + lquad;              // 16B chunk wanted
#pragma unroll
            for (int i = 0; i < 4; ++i)
                af[i] = *(const bf16x8_t*)(As + (wr + i * 16 + lrow) * BK + ((kc ^ l7) * 8));
#pragma unroll
            for (int j = 0; j < 4; ++j)
                bf[j] = *(const bf16x8_t*)(Bs + (wc + j * 16 + lrow) * BK + ((kc ^ l7) * 8));
#pragma unroll
            for (int i = 0; i < 4; ++i)
#pragma unroll
                for (int j = 0; j < 4; ++j)
                    gacc[i][j] = __builtin_amdgcn_mfma_f32_16x16x32_bf16(
                        af[i], bf[j], gacc[i][j], 0, 0, 0);
        }

        if (kt & 1) {                          // end of a 128-wide K group
            const int g = kt >> 1;
#pragma unroll
            for (int j = 0; j < 4; ++j) {
                const int n = bn * BN + wc + j * 16 + lrow;
                const float scl = wscales[n * NGROUP + g];
#pragma unroll
                for (int i = 0; i < 4; ++i) {
                    cacc[i][j] += gacc[i][j] * scl;
                    gacc[i][j] = zero4;
                }
            }
        }
    }

    // Epilogue: C/D layout col=lane&15, row=lquad*4+reg  [m89/m91 verified]
    const int m0 = bm * BM + wr;
    const int n0 = bn * BN + wc;
#pragma unroll
    for (int i = 0; i < 4; ++i) {
#pragma unroll
        for (int r = 0; r < 4; ++r) {
            const int m = m0 + i * 16 + lquad * 4 + r;
            const float xs = xscale[m];
#pragma unroll
            for (int j = 0; j < 4; ++j) {
                const int n = n0 + j * 16 + lrow;
                out[(size_t)m * N_DIM + n] = cacc[i][j][r] * xs + bias[n];
            }
        }
    }
}

extern "C" void kernel_launch(void* const* d_in, const int* in_sizes, int n_in,
                              void* d_out, int out_size, void* d_ws, size_t ws_size,
                              hipStream_t stream) {
    const float* x     = (const float*)d_in[0];
    const int*   qw    = (const int*)d_in[1];
    const float* wsc   = (const float*)d_in[2];
    const int*   wzp   = (const int*)d_in[3];
    const float* bias  = (const float*)d_in[4];
    float* out = (float*)d_out;

    // workspace layout
    unsigned short* A = (unsigned short*)d_ws;                           // 16 MiB
    float* xscale = (float*)((char*)d_ws + (size_t)M_DIM * K_DIM * 2);   // 8 KiB
    unsigned short* Bt = (unsigned short*)((char*)xscale + M_DIM * 4);   // 32 MiB

    prep_kernel<<<QUANT_BLOCKS + DEQ_BLOCKS, 256, 0, stream>>>(x, qw, wzp, A, Bt, xscale);
    dim3 grid(N_DIM / BN, M_DIM / BM);
    gemm_kernel<<<grid, 256, 0, stream>>>(A, Bt, xscale, wsc, bias, out);
}

// Round 3
// 202.012 us; speedup vs baseline: 1.1511x; 1.0993x over previous
//
#include <hip/hip_runtime.h>
#include <hip/hip_bf16.h>
#include <stdint.h>

#define M_DIM 2048
#define N_DIM 4096
#define K_DIM 4096
#define NGROUP 32
#define GSIZE 128

// GEMM tiling (i8 path): BK = 128 codes = one quant group per stage.
#define BM 128
#define BN 64
#define BKB 128        // bytes per LDS row (128 i8) = 8 chunks of 16 B

typedef __attribute__((ext_vector_type(4))) int   int32x4_t;
typedef __attribute__((ext_vector_type(4))) float f32x4_t;

// global -> LDS direct DMA, 16 B per lane. LDS dst is wave-uniform base +
// lane*16 (m104/m108); data placement chosen via per-lane global address.
static __device__ __forceinline__ void gl2lds16(const void* g, void* l) {
    auto gp = (const __attribute__((address_space(1))) unsigned int*)(uintptr_t)g;
    auto lp = (__attribute__((address_space(3))) unsigned int*)(uintptr_t)l;
    __builtin_amdgcn_global_load_lds(gp, lp, 16, 0, 0);
}

// ---------------------------------------------------------------------------
// Fused prep, three block ranges:
//   [0, 2048): per-token activation quant -> A8 = (q-128) int8, xscale, czp
//   [2048, 2048+8192): weight dequant -> Bt8 = (code-wzp) int8, and
//        group sums Sw folded into WS[n] += ws[n][g]*Sw[n][g] via atomics
//   [.., +512): wscales transpose -> wsct[g][n] for coalesced GEMM fold reads
// ---------------------------------------------------------------------------
#define QUANT_BLOCKS M_DIM
#define DEQ_BLOCKS ((N_DIM * K_DIM) / 8 / 256)       // 8 codes / thread
#define WT_BLOCKS ((N_DIM * NGROUP) / 256)           // 1 elem / thread

__global__ __launch_bounds__(256) void prep_kernel(
        const float* __restrict__ x,
        const int* __restrict__ qw,          // [N][K] codes 0..15 as int32
        const float* __restrict__ wsc,       // [N][32]
        const int* __restrict__ wzp,         // [N][32]
        char* __restrict__ A8,               // [M][K] int8 (q-128)
        char* __restrict__ Bt8,              // [N][K] int8 (code-wzp)
        float* __restrict__ xscale,          // [M]
        float* __restrict__ xzpc,            // [M]  = 128 - zp
        float* __restrict__ WS,              // [N]  (pre-zeroed; atomics)
        float* __restrict__ wsct)            // [32][N] transposed scales
{
    const int t = threadIdx.x;
    if (blockIdx.x < QUANT_BLOCKS) {
        // ---- per-token asymmetric quantization, one block per token ----
        const int s = blockIdx.x;
        const float* xrow = x + (size_t)s * K_DIM;

        float xv[16];
        float vmin = 1e38f, vmax = -1e38f;
#pragma unroll
        for (int p = 0; p < 4; ++p) {
            float4 v = *((const float4*)(xrow + p * 1024) + t);
            xv[p*4+0] = v.x; xv[p*4+1] = v.y; xv[p*4+2] = v.z; xv[p*4+3] = v.w;
            vmin = fminf(vmin, fminf(fminf(v.x, v.y), fminf(v.z, v.w)));
            vmax = fmaxf(vmax, fmaxf(fmaxf(v.x, v.y), fmaxf(v.z, v.w)));
        }
#pragma unroll
        for (int off = 32; off > 0; off >>= 1) {
            vmin = fminf(vmin, __shfl_xor(vmin, off));
            vmax = fmaxf(vmax, __shfl_xor(vmax, off));
        }
        __shared__ float smin[4], smax[4];
        const int wave = t >> 6;
        if ((t & 63) == 0) { smin[wave] = vmin; smax[wave] = vmax; }
        __syncthreads();
        vmin = fminf(fminf(smin[0], smin[1]), fminf(smin[2], smin[3]));
        vmax = fmaxf(fmaxf(smax[0], smax[1]), fmaxf(smax[2], smax[3]));

        float sc = (vmax - vmin) / 255.0f;
        sc = fmaxf(sc, 1e-5f);
        float zp = rintf(-vmin / sc);
        zp = fminf(fmaxf(zp, 0.0f), 255.0f);

#pragma unroll
        for (int p = 0; p < 4; ++p) {
            int b[4];
#pragma unroll
            for (int e = 0; e < 4; ++e) {
                float q = fminf(fmaxf(rintf(xv[p*4+e] / sc) + zp, 0.0f), 255.0f);
                b[e] = (int)q - 128;
            }
            unsigned pack = (b[0] & 0xff) | ((b[1] & 0xff) << 8) |
                            ((b[2] & 0xff) << 16) | ((b[3] & 0xff) << 24);
            *(unsigned*)(A8 + (size_t)s * K_DIM + p * 1024 + t * 4) = pack;
        }
        if (t == 0) { xscale[s] = sc; xzpc[s] = 128.0f - zp; }
    } else if (blockIdx.x < QUANT_BLOCKS + DEQ_BLOCKS) {
        // ---- weight dequant: 8 codes/thread; 16-lane cluster = 1 group ----
        const size_t base = ((size_t)(blockIdx.x - QUANT_BLOCKS) * 256 + t) * 8;
        const int n = (int)(base >> 12);          // /4096
        const int g = (int)((base >> 7) & 31);
        const int zp = wzp[n * NGROUP + g];

        int4 c0 = *(const int4*)(qw + base);
        int4 c1 = *(const int4*)(qw + base + 4);
        int v0 = c0.x - zp, v1 = c0.y - zp, v2 = c0.z - zp, v3 = c0.w - zp;
        int v4 = c1.x - zp, v5 = c1.y - zp, v6 = c1.z - zp, v7 = c1.w - zp;
        uint2 pk;
        pk.x = (v0 & 0xff) | ((v1 & 0xff) << 8) | ((v2 & 0xff) << 16) | ((v3 & 0xff) << 24);
        pk.y = (v4 & 0xff) | ((v5 & 0xff) << 8) | ((v6 & 0xff) << 16) | ((v7 & 0xff) << 24);
        *(uint2*)(Bt8 + base) = pk;

        int s8 = v0 + v1 + v2 + v3 + v4 + v5 + v6 + v7;
#pragma unroll
        for (int off = 1; off < 16; off <<= 1) s8 += __shfl_xor(s8, off);
        if ((t & 15) == 0)
            atomicAdd(WS + n, wsc[n * NGROUP + g] * (float)s8);
    } else {
        // ---- wscales transpose ----
        const int idx = (blockIdx.x - QUANT_BLOCKS - DEQ_BLOCKS) * 256 + t;
        const int n = idx >> 5, g = idx & 31;
        wsct[g * N_DIM + n] = wsc[idx];
    }
}

// ---------------------------------------------------------------------------
// i8 grouped GEMM. Per stage kt (= group g): iacc += A8 x Bt8 (i32, exact),
// then facc += wsct[g][n] * (float)iacc. Epilogue:
//   out[m][n] = xscale[m] * (facc + czp[m]*WS[n]) + bias[n]
// 128x64 tile, 4 waves each 64x32 (4x2 of 16x16x64 i8 MFMA).
// LDS: row-major [rows][128B], chunk c of row r stored at slot c^(r&7)
// (verified conflict-free pattern from R2). Staged via global_load_lds.
// ---------------------------------------------------------------------------
__global__ __launch_bounds__(256, 4) void gemm_kernel(
        const char* __restrict__ A8,     // [M][K] int8
        const char* __restrict__ Bt8,    // [N][K] int8
        const float* __restrict__ xscale,
        const float* __restrict__ xzpc,
        const float* __restrict__ wsct,  // [32][N]
        const float* __restrict__ WS,    // [N]
        const float* __restrict__ bias,  // [N]
        float* __restrict__ out)         // [M][N] f32
{
    __shared__ __align__(16) char As[BM * BKB];   // 16 KiB
    __shared__ __align__(16) char Bs[BN * BKB];   // 8 KiB

    const int tid  = threadIdx.x;
    const int bm   = blockIdx.y;
    const int bn   = blockIdx.x;
    const int wave = tid >> 6;
    const int lane = tid & 63;
    const int wr   = (wave >> 1) * 64;   // wave row offset in 128
    const int wc   = (wave & 1) * 32;    // wave col offset in 64
    const int lrow  = lane & 15;
    const int lquad = lane >> 4;         // 0..3
    const int l7    = lrow & 7;

    const int srow8 = lane >> 3;         // row within 8-row slab
    const int cdat  = (lane & 7) ^ srow8; // source 16B chunk for this slot

    int32x4_t iacc[4][2];
    f32x4_t   facc[4][2];
    const int32x4_t zi = {0, 0, 0, 0};
    const f32x4_t   zf = {0.f, 0.f, 0.f, 0.f};
#pragma unroll
    for (int i = 0; i < 4; ++i)
#pragma unroll
        for (int j = 0; j < 2; ++j) { iacc[i][j] = zi; facc[i][j] = zf; }

    const char* Ab = A8  + (size_t)(bm * BM) * K_DIM;
    const char* Bb = Bt8 + (size_t)(bn * BN) * K_DIM;

    for (int kt = 0; kt < K_DIM / GSIZE; ++kt) {   // 32 stages, 1 group each
        const int k0 = kt * GSIZE;                 // byte == elem offset (i8)
        __syncthreads();
        // A: 16 slabs of 8 rows; wave handles 4. B: 8 slabs; wave handles 2.
#pragma unroll
        for (int p = 0; p < 4; ++p) {
            const int rbase = (p * 4 + wave) * 8;           // wave-uniform
            gl2lds16(Ab + (size_t)(rbase + srow8) * K_DIM + k0 + cdat * 16,
                     As + rbase * BKB);
        }
#pragma unroll
        for (int p = 0; p < 2; ++p) {
            const int rbase = (p * 4 + wave) * 8;
            gl2lds16(Bb + (size_t)(rbase + srow8) * K_DIM + k0 + cdat * 16,
                     Bs + rbase * BKB);
        }
        __syncthreads();

#pragma unroll
        for (int ks = 0; ks < 2; ++ks) {
            const int kc = ks * 4 + lquad;          // wanted 16B chunk
            int32x4_t af[4], bf[2];
#pragma unroll
            for (int i = 0; i < 4; ++i)
                af[i] = *(const int32x4_t*)(As + (wr + i * 16 + lrow) * BKB + ((kc ^ l7) * 16));
#pragma unroll
            for (int j = 0; j < 2; ++j)
                bf[j] = *(const int32x4_t*)(Bs + (wc + j * 16 + lrow) * BKB + ((kc ^ l7) * 16));
#pragma unroll
            for (int i = 0; i < 4; ++i)
#pragma unroll
                for (int j = 0; j < 2; ++j)
                    iacc[i][j] = __builtin_amdgcn_mfma_i32_16x16x64_i8(
                        af[i], bf[j], iacc[i][j], 0, 0, 0);
        }

        // fold this group's integer acc with its weight scale
#pragma unroll
        for (int j = 0; j < 2; ++j) {
            const int n = bn * BN + wc + j * 16 + lrow;
            const float scl = wsct[kt * N_DIM + n];
#pragma unroll
            for (int i = 0; i < 4; ++i) {
#pragma unroll
                for (int r = 0; r < 4; ++r)
                    facc[i][j][r] += scl * (float)iacc[i][j][r];
                iacc[i][j] = zi;
            }
        }
    }

    // Epilogue: C/D layout col=lane&15, row=lquad*4+reg (dtype-independent)
    const int m0 = bm * BM + wr;
    const int n0 = bn * BN + wc;
    float wsn[2], bn2[2];
#pragma unroll
    for (int j = 0; j < 2; ++j) {
        const int n = n0 + j * 16 + lrow;
        wsn[j] = WS[n]; bn2[j] = bias[n];
    }
#pragma unroll
    for (int i = 0; i < 4; ++i) {
#pragma unroll
        for (int r = 0; r < 4; ++r) {
            const int m = m0 + i * 16 + lquad * 4 + r;
            const float xs = xscale[m];
            const float czp = xzpc[m];
#pragma unroll
            for (int j = 0; j < 2; ++j) {
                const int n = n0 + j * 16 + lrow;
                out[(size_t)m * N_DIM + n] = xs * (facc[i][j][r] + czp * wsn[j]) + bn2[j];
            }
        }
    }
}

extern "C" void kernel_launch(void* const* d_in, const int* in_sizes, int n_in,
                              void* d_out, int out_size, void* d_ws, size_t ws_size,
                              hipStream_t stream) {
    const float* x     = (const float*)d_in[0];
    const int*   qw    = (const int*)d_in[1];
    const float* wsc   = (const float*)d_in[2];
    const int*   wzp   = (const int*)d_in[3];
    const float* bias  = (const float*)d_in[4];
    float* out = (float*)d_out;

    // workspace layout
    char* A8  = (char*)d_ws;                                   //  8 MiB
    char* Bt8 = A8 + (size_t)M_DIM * K_DIM;                    // 16 MiB
    float* xscale = (float*)(Bt8 + (size_t)N_DIM * K_DIM);     //  8 KiB
    float* xzpc   = xscale + M_DIM;                            //  8 KiB
    float* WS     = xzpc + M_DIM;                              // 16 KiB
    float* wsct   = WS + N_DIM;                                // 512 KiB

    hipMemsetAsync(WS, 0, N_DIM * sizeof(float), stream);
    prep_kernel<<<QUANT_BLOCKS + DEQ_BLOCKS + WT_BLOCKS, 256, 0, stream>>>(
        x, qw, wsc, wzp, A8, Bt8, xscale, xzpc, WS, wsct);
    dim3 grid(N_DIM / BN, M_DIM / BM);
    gemm_kernel<<<grid, 256, 0, stream>>>(A8, Bt8, xscale, xzpc, wsct, WS, bias, out);
}